// Round 3
// baseline (264.625 us; speedup 1.0000x reference)
//
#include <hip/hip_runtime.h>
#include <stdint.h>

#define AS1 __attribute__((address_space(1)))
#define AS3 __attribute__((address_space(3)))

typedef __bf16 bf16x8 __attribute__((ext_vector_type(8)));
typedef float f32x4 __attribute__((ext_vector_type(4)));

constexpr int NB = 8;     // batches
constexpr int N  = 2048;  // nodes
constexpr int F  = 128;   // features (in == out)

__device__ __forceinline__ unsigned short bf16r(float f) {
    unsigned u = __float_as_uint(f);
    return (unsigned short)((u + 0x7FFFu + ((u >> 16) & 1u)) >> 16);
}
__device__ __forceinline__ float bf2f(unsigned short s) {
    return __uint_as_float(((unsigned)s) << 16);
}

// ---------------------------------------------------------------------------
// Wb2 element layout (MFMA-B-operand native, linear in k-chunks):
//   byte(b, n, o) = b*N*F*2 + (n>>3)*2048 + o*16 + (n&7)*2
// BK=32 chunk c = contiguous 8192 B at b*N*F*2 + c*8192.
// ---------------------------------------------------------------------------

// K1 (fused): Wh = h @ W^T;  e = Wh @ a2;  p = exp(e);
//   p16 = bf16(p);  Wb2 = bf16(bf2f(p16) * Wh)        [unchanged, proven]
__global__ __launch_bounds__(256) void k1_wh(const float* __restrict__ h,
                                             const float* __restrict__ W,
                                             const float* __restrict__ a,
                                             unsigned short* __restrict__ Wb2,
                                             unsigned short* __restrict__ p16) {
    __shared__ float epart[2][64];

    const int tid  = threadIdx.x;
    const int lane = tid & 63, wid = tid >> 6;
    const int quad = lane >> 4, l15 = lane & 15;
    const int wm = wid >> 1, wn = wid & 1;
    const int m0 = blockIdx.x * 64;
    const int batch = m0 >> 11;
    const int nbase = m0 & 2047;

    f32x4 acc[2][4] = {};

#pragma unroll
    for (int kk = 0; kk < 4; ++kk) {
        const int k = kk * 32 + quad * 8;
        bf16x8 afr[2], bfr[4];
#pragma unroll
        for (int rt = 0; rt < 2; ++rt) {
            const float* src = h + (size_t)(m0 + wm * 32 + rt * 16 + l15) * F + k;
            float4 x0 = *(const float4*)src;
            float4 x1 = *(const float4*)(src + 4);
            afr[rt][0] = (__bf16)x0.x; afr[rt][1] = (__bf16)x0.y;
            afr[rt][2] = (__bf16)x0.z; afr[rt][3] = (__bf16)x0.w;
            afr[rt][4] = (__bf16)x1.x; afr[rt][5] = (__bf16)x1.y;
            afr[rt][6] = (__bf16)x1.z; afr[rt][7] = (__bf16)x1.w;
        }
#pragma unroll
        for (int ct = 0; ct < 4; ++ct) {
            const int o = wn * 64 + ct * 16 + l15;
            const float* src = W + (size_t)o * F + k;
            float4 x0 = *(const float4*)src;
            float4 x1 = *(const float4*)(src + 4);
            bfr[ct][0] = (__bf16)x0.x; bfr[ct][1] = (__bf16)x0.y;
            bfr[ct][2] = (__bf16)x0.z; bfr[ct][3] = (__bf16)x0.w;
            bfr[ct][4] = (__bf16)x1.x; bfr[ct][5] = (__bf16)x1.y;
            bfr[ct][6] = (__bf16)x1.z; bfr[ct][7] = (__bf16)x1.w;
        }
#pragma unroll
        for (int rt = 0; rt < 2; ++rt)
#pragma unroll
            for (int ct = 0; ct < 4; ++ct)
                acc[rt][ct] = __builtin_amdgcn_mfma_f32_16x16x32_bf16(
                    afr[rt], bfr[ct], acc[rt][ct], 0, 0, 0);
    }

    float a2v[4];
#pragma unroll
    for (int ct = 0; ct < 4; ++ct) a2v[ct] = a[F + wn * 64 + ct * 16 + l15];

    float ep[2][4];
#pragma unroll
    for (int rt = 0; rt < 2; ++rt)
#pragma unroll
        for (int g = 0; g < 4; ++g) {
            float s = 0.f;
#pragma unroll
            for (int ct = 0; ct < 4; ++ct) s += acc[rt][ct][g] * a2v[ct];
            ep[rt][g] = s;
        }
#pragma unroll
    for (int m = 1; m < 16; m <<= 1)
#pragma unroll
        for (int rt = 0; rt < 2; ++rt)
#pragma unroll
            for (int g = 0; g < 4; ++g)
                ep[rt][g] += __shfl_xor(ep[rt][g], m);

    if (l15 == 0)
#pragma unroll
        for (int rt = 0; rt < 2; ++rt)
#pragma unroll
            for (int g = 0; g < 4; ++g)
                epart[wn][wm * 32 + rt * 16 + quad * 4 + g] = ep[rt][g];
    __syncthreads();

#pragma unroll
    for (int rt = 0; rt < 2; ++rt)
#pragma unroll
        for (int ct = 0; ct < 4; ++ct) {
            const int o  = wn * 64 + ct * 16 + l15;
            const int r0 = wm * 32 + rt * 16 + quad * 4;
            const int n0 = nbase + r0;
            ushort4 v;
#pragma unroll
            for (int g = 0; g < 4; ++g) {
                const float e  = epart[0][r0 + g] + epart[1][r0 + g];
                const float pf = bf2f(bf16r(expf(e)));
                (&v.x)[g] = bf16r(pf * acc[rt][ct][g]);
            }
            size_t off = (size_t)batch * N * F + (size_t)(n0 >> 3) * 1024 + o * 8 + (n0 & 7);
            *(ushort4*)&Wb2[off] = v;
        }

    if (tid < 64) {
        const float e = epart[0][tid] + epart[1][tid];
        p16[batch * N + nbase + tid] = bf16r(expf(e));
    }
}

// K3'' (fused, LDS-free, barrier-free, high-occupancy):
//   out[b][i][o] = (sum_j adj[b][i][j]*Wb2[j][o]) / (sum_j adj[b][i][j]*p[j])
// R2 PMC: 78 us @ 12% HBM, Occ 19.5%, Mfma 5% -> latency-bound (512 blocks =
// 2 blk/CU = 8 waves/CU, depth-1 prefetch). Fix: 16-row blocks, 4 waves each
// owning a 32-wide o-quarter -> grid 1024 = 4 blk/CU = 16 waves/CU (50% occ),
// plus 2-slot hand-unrolled prefetch (2 chunks deep) on all streams.
// A fragment is re-read by all 4 waves (L2 hit after first miss; HBM traffic
// unchanged); denominator MFMA duplicated per wave (trivial) -> still zero
// LDS, zero barriers. dacc C/D layout (row = quad*4+g) keeps each row's
// denominator in every lane owning that row -> divide in-register.
__global__ __launch_bounds__(256, 4) void k3_fused(const float* __restrict__ adj,
                                                   const unsigned short* __restrict__ Wb2,
                                                   const unsigned short* __restrict__ p16,
                                                   float* __restrict__ out) {
    const int tid  = threadIdx.x;
    const int lane = tid & 63, wid = tid >> 6;   // wid = o-quarter 0..3
    const int quad = lane >> 4, l15 = lane & 15;
    const int b  = blockIdx.x & 7;               // XCD pin
    const int it = blockIdx.x >> 3;              // 0..127
    const int i0 = it * 16;
    const int rowA = i0 + l15;                   // the adj row this lane streams

    const float* aP = adj + (size_t)b * N * N + (size_t)rowA * N + quad * 8;
    const char*  bP = (const char*)Wb2 + (size_t)b * (N * F * 2)
                    + quad * 2048 + wid * 512 + l15 * 16;
    const char*  pP = (const char*)p16 + (size_t)b * N * 2 + quad * 16;

    f32x4 acc0 = {}, acc1 = {};
    f32x4 dacc = {0.f, 0.f, 0.f, 0.f};

    // 2-slot prefetch: slot0 holds even chunks, slot1 odd chunks.
    f32x4  aS0_0 = *(const f32x4*)(aP);
    f32x4  aS0_1 = *(const f32x4*)(aP + 4);
    f32x4  aS1_0 = *(const f32x4*)(aP + 32);
    f32x4  aS1_1 = *(const f32x4*)(aP + 36);
    bf16x8 bS0_0 = *(const bf16x8*)(bP);
    bf16x8 bS0_1 = *(const bf16x8*)(bP + 256);
    bf16x8 bS1_0 = *(const bf16x8*)(bP + 8192);
    bf16x8 bS1_1 = *(const bf16x8*)(bP + 8192 + 256);
    bf16x8 pS0   = *(const bf16x8*)(pP);
    bf16x8 pS1   = *(const bf16x8*)(pP + 64);

#define K3_BODY(SA0, SA1, SB0, SB1, SP, CNEXT, GUARD)                          \
    {                                                                          \
        f32x4  a0_ = SA0, a1_ = SA1;                                           \
        bf16x8 cb0_ = SB0, cb1_ = SB1, cpv_ = SP;                              \
        if (GUARD) {                                                           \
            const float* aN_ = aP + (size_t)(CNEXT) * 32;                      \
            SA0 = *(const f32x4*)(aN_);                                        \
            SA1 = *(const f32x4*)(aN_ + 4);                                    \
            const char* bN_ = bP + (size_t)(CNEXT) * 8192;                     \
            SB0 = *(const bf16x8*)(bN_);                                       \
            SB1 = *(const bf16x8*)(bN_ + 256);                                 \
            SP  = *(const bf16x8*)(pP + (size_t)(CNEXT) * 64);                 \
        }                                                                      \
        bf16x8 af_;                                                            \
        af_[0] = (__bf16)a0_[0]; af_[1] = (__bf16)a0_[1];                      \
        af_[2] = (__bf16)a0_[2]; af_[3] = (__bf16)a0_[3];                      \
        af_[4] = (__bf16)a1_[0]; af_[5] = (__bf16)a1_[1];                      \
        af_[6] = (__bf16)a1_[2]; af_[7] = (__bf16)a1_[3];                      \
        acc0 = __builtin_amdgcn_mfma_f32_16x16x32_bf16(af_, cb0_, acc0, 0, 0, 0); \
        acc1 = __builtin_amdgcn_mfma_f32_16x16x32_bf16(af_, cb1_, acc1, 0, 0, 0); \
        dacc = __builtin_amdgcn_mfma_f32_16x16x32_bf16(af_, cpv_, dacc, 0, 0, 0); \
    }

    for (int c = 0; c < 64; c += 2) {
        K3_BODY(aS0_0, aS0_1, bS0_0, bS0_1, pS0, c + 2, (c + 2 < 64))
        K3_BODY(aS1_0, aS1_1, bS1_0, bS1_1, pS1, c + 3, (c + 3 < 64))
    }
#undef K3_BODY

    // Epilogue: divide by per-row denominator (in-lane) and store final f32.
#pragma unroll
    for (int g = 0; g < 4; ++g) {
        const float inv = 1.0f / dacc[g];
        float* orow = out + ((size_t)b * N + i0 + quad * 4 + g) * F
                    + wid * 32 + l15;
        orow[0]  = acc0[g] * inv;
        orow[16] = acc1[g] * inv;
    }
}

// ---------------------------------------------------------------------------
extern "C" void kernel_launch(void* const* d_in, const int* in_sizes, int n_in,
                              void* d_out, int out_size, void* d_ws, size_t ws_size,
                              hipStream_t stream) {
    const float* h   = (const float*)d_in[0];
    const float* adj = (const float*)d_in[1];
    const float* W   = (const float*)d_in[2];
    const float* a   = (const float*)d_in[3];
    float* out = (float*)d_out;

    unsigned short* Wb2 = (unsigned short*)d_ws;                        // 4 MB
    unsigned short* p16 = (unsigned short*)((char*)d_ws + (4u << 20));  // 32 KB

    k1_wh<<<NB * N / 64, 256, 0, stream>>>(h, W, a, Wb2, p16);
    k3_fused<<<NB * 64 * 2, 256, 0, stream>>>(adj, Wb2, p16, out);
}

// Round 4
// 231.499 us; speedup vs baseline: 1.1431x; 1.1431x over previous
//
#include <hip/hip_runtime.h>
#include <stdint.h>

#define AS1 __attribute__((address_space(1)))
#define AS3 __attribute__((address_space(3)))

typedef __bf16 bf16x8 __attribute__((ext_vector_type(8)));
typedef float f32x4 __attribute__((ext_vector_type(4)));

constexpr int NB = 8;     // batches
constexpr int N  = 2048;  // nodes
constexpr int F  = 128;   // features (in == out)

__device__ __forceinline__ unsigned short bf16r(float f) {
    unsigned u = __float_as_uint(f);
    return (unsigned short)((u + 0x7FFFu + ((u >> 16) & 1u)) >> 16);
}
__device__ __forceinline__ float bf2f(unsigned short s) {
    return __uint_as_float(((unsigned)s) << 16);
}

// ---------------------------------------------------------------------------
// Wb2 element layout (MFMA-B-operand native, linear in k-chunks):
//   byte(b, n, o) = b*N*F*2 + (n>>3)*2048 + o*16 + (n&7)*2
// BK=32 chunk c = contiguous 8192 B at b*N*F*2 + c*8192.
// ---------------------------------------------------------------------------

// K1 (fused): Wh = h @ W^T;  e = Wh @ a2;  p = exp(e);
//   p16 = bf16(p);  Wb2 = bf16(bf2f(p16) * Wh)        [unchanged, proven]
__global__ __launch_bounds__(256) void k1_wh(const float* __restrict__ h,
                                             const float* __restrict__ W,
                                             const float* __restrict__ a,
                                             unsigned short* __restrict__ Wb2,
                                             unsigned short* __restrict__ p16) {
    __shared__ float epart[2][64];

    const int tid  = threadIdx.x;
    const int lane = tid & 63, wid = tid >> 6;
    const int quad = lane >> 4, l15 = lane & 15;
    const int wm = wid >> 1, wn = wid & 1;
    const int m0 = blockIdx.x * 64;
    const int batch = m0 >> 11;
    const int nbase = m0 & 2047;

    f32x4 acc[2][4] = {};

#pragma unroll
    for (int kk = 0; kk < 4; ++kk) {
        const int k = kk * 32 + quad * 8;
        bf16x8 afr[2], bfr[4];
#pragma unroll
        for (int rt = 0; rt < 2; ++rt) {
            const float* src = h + (size_t)(m0 + wm * 32 + rt * 16 + l15) * F + k;
            float4 x0 = *(const float4*)src;
            float4 x1 = *(const float4*)(src + 4);
            afr[rt][0] = (__bf16)x0.x; afr[rt][1] = (__bf16)x0.y;
            afr[rt][2] = (__bf16)x0.z; afr[rt][3] = (__bf16)x0.w;
            afr[rt][4] = (__bf16)x1.x; afr[rt][5] = (__bf16)x1.y;
            afr[rt][6] = (__bf16)x1.z; afr[rt][7] = (__bf16)x1.w;
        }
#pragma unroll
        for (int ct = 0; ct < 4; ++ct) {
            const int o = wn * 64 + ct * 16 + l15;
            const float* src = W + (size_t)o * F + k;
            float4 x0 = *(const float4*)src;
            float4 x1 = *(const float4*)(src + 4);
            bfr[ct][0] = (__bf16)x0.x; bfr[ct][1] = (__bf16)x0.y;
            bfr[ct][2] = (__bf16)x0.z; bfr[ct][3] = (__bf16)x0.w;
            bfr[ct][4] = (__bf16)x1.x; bfr[ct][5] = (__bf16)x1.y;
            bfr[ct][6] = (__bf16)x1.z; bfr[ct][7] = (__bf16)x1.w;
        }
#pragma unroll
        for (int rt = 0; rt < 2; ++rt)
#pragma unroll
            for (int ct = 0; ct < 4; ++ct)
                acc[rt][ct] = __builtin_amdgcn_mfma_f32_16x16x32_bf16(
                    afr[rt], bfr[ct], acc[rt][ct], 0, 0, 0);
    }

    float a2v[4];
#pragma unroll
    for (int ct = 0; ct < 4; ++ct) a2v[ct] = a[F + wn * 64 + ct * 16 + l15];

    float ep[2][4];
#pragma unroll
    for (int rt = 0; rt < 2; ++rt)
#pragma unroll
        for (int g = 0; g < 4; ++g) {
            float s = 0.f;
#pragma unroll
            for (int ct = 0; ct < 4; ++ct) s += acc[rt][ct][g] * a2v[ct];
            ep[rt][g] = s;
        }
#pragma unroll
    for (int m = 1; m < 16; m <<= 1)
#pragma unroll
        for (int rt = 0; rt < 2; ++rt)
#pragma unroll
            for (int g = 0; g < 4; ++g)
                ep[rt][g] += __shfl_xor(ep[rt][g], m);

    if (l15 == 0)
#pragma unroll
        for (int rt = 0; rt < 2; ++rt)
#pragma unroll
            for (int g = 0; g < 4; ++g)
                epart[wn][wm * 32 + rt * 16 + quad * 4 + g] = ep[rt][g];
    __syncthreads();

#pragma unroll
    for (int rt = 0; rt < 2; ++rt)
#pragma unroll
        for (int ct = 0; ct < 4; ++ct) {
            const int o  = wn * 64 + ct * 16 + l15;
            const int r0 = wm * 32 + rt * 16 + quad * 4;
            const int n0 = nbase + r0;
            ushort4 v;
#pragma unroll
            for (int g = 0; g < 4; ++g) {
                const float e  = epart[0][r0 + g] + epart[1][r0 + g];
                const float pf = bf2f(bf16r(expf(e)));
                (&v.x)[g] = bf16r(pf * acc[rt][ct][g]);
            }
            size_t off = (size_t)batch * N * F + (size_t)(n0 >> 3) * 1024 + o * 8 + (n0 & 7);
            *(ushort4*)&Wb2[off] = v;
        }

    if (tid < 64) {
        const float e = epart[0][tid] + epart[1][tid];
        p16[batch * N + nbase + tid] = bf16r(expf(e));
    }
}

// K3 v3: wave-private LDS pipeline, ZERO per-chunk barriers, counted vmcnt.
//   out[b][i][o] = (sum_j adj[b][i][j]*Wb2[j][o]) / (sum_j adj[b][i][j]*p[j])
// R2/R3 post-mortem: register prefetch was compiler-sunk (VGPR=48 < the 66+
// the pipeline needs) -> serial latency chain, 78/109 us. Fix: staging via
// global_load_lds (not sinkable), each wave owns PRIVATE A/B buffers 3 deep,
// consumption gated by inline s_waitcnt vmcnt(N) (N = 6 loads/chunk x newer
// chunks in flight) -> no __syncthreads, no vmcnt(0) drain (the R0 stall).
// Block = 32 rows, 4 waves = 2x2 (wm 16-row half x wn 64-col half). Grid 512,
// b = blk&7 XCD-pins batch (Wb2 slice 512 KB L2-resident). LDS/block:
// A 4x3x2KB + B 4x3x4KB + p 4KB = 76 KB -> 2 blocks/CU, 8 waves/CU; in-flight
// HBM ~48 KB/CU >> ~9 KB BW*latency product. A staged with R0's proven XOR
// pre-swizzle (slot lane&7 holds global chunk (lane&7)^(row&7)); B staged
// linear (Wb2 image is MFMA-native). Stage(c+3) issued only after lgkmcnt(0)
// (buffer fully consumed) -> WAR reuse race structurally impossible.
__global__ __launch_bounds__(256, 2) void k3_fused(const float* __restrict__ adj,
                                                   const unsigned short* __restrict__ Wb2,
                                                   const unsigned short* __restrict__ p16,
                                                   float* __restrict__ out) {
    __shared__ __align__(16) char Asm_[4][3][2048];
    __shared__ __align__(16) char Bsm_[4][3][4096];
    __shared__ __align__(16) char Psm_[4096];

    const int tid  = threadIdx.x;
    const int lane = tid & 63, wid = tid >> 6;
    const int quad = lane >> 4, l15 = lane & 15;
    const int wm = wid >> 1, wn = wid & 1;
    const int b  = blockIdx.x & 7;
    const int it = blockIdx.x >> 3;        // 0..63
    const int i0 = it * 32;
    const int row0 = i0 + wm * 16;

    // p16 (4 KB/batch): staged once by wave 0; the only barrier in the kernel.
    if (wid == 0) {
#pragma unroll
        for (int s = 0; s < 4; ++s)
            __builtin_amdgcn_global_load_lds(
                (const AS1 void*)((const char*)p16 + (size_t)b * N * 2 + s * 1024 + lane * 16),
                (AS3 void*)(&Psm_[s * 1024]), 16, 0, 0);
    }
    __syncthreads();

    // A sources, pre-swizzled (m173 pattern): gll instr s covers rows
    // s*8+(lane>>3); 16B slot (lane&7) receives global chunk (lane&7)^(ri&7).
    const float* aSrc0, *aSrc1;
    {
        const int r0_ = (lane >> 3), r1_ = 8 + (lane >> 3);
        aSrc0 = adj + (size_t)b * N * N + (size_t)(row0 + r0_) * N
              + (((lane & 7) ^ (r0_ & 7)) << 2);
        aSrc1 = adj + (size_t)b * N * N + (size_t)(row0 + r1_) * N
              + (((lane & 7) ^ (r1_ & 7)) << 2);
    }
    // B source: wave's 64-col half = 4 x 1KB slices per 8KB chunk.
    const char* bSrc = (const char*)Wb2 + (size_t)b * (N * F * 2)
                     + wn * 1024 + lane * 16;

#define K3_STAGE(BI, C)                                                          \
    do {                                                                         \
        __builtin_amdgcn_global_load_lds((const AS1 void*)(aSrc0 + (C) * 32),    \
            (AS3 void*)(&Asm_[wid][BI][0]),    16, 0, 0);                        \
        __builtin_amdgcn_global_load_lds((const AS1 void*)(aSrc1 + (C) * 32),    \
            (AS3 void*)(&Asm_[wid][BI][1024]), 16, 0, 0);                        \
        __builtin_amdgcn_global_load_lds((const AS1 void*)(bSrc + (size_t)(C) * 8192 + 0),    \
            (AS3 void*)(&Bsm_[wid][BI][0]),    16, 0, 0);                        \
        __builtin_amdgcn_global_load_lds((const AS1 void*)(bSrc + (size_t)(C) * 8192 + 2048), \
            (AS3 void*)(&Bsm_[wid][BI][1024]), 16, 0, 0);                        \
        __builtin_amdgcn_global_load_lds((const AS1 void*)(bSrc + (size_t)(C) * 8192 + 4096), \
            (AS3 void*)(&Bsm_[wid][BI][2048]), 16, 0, 0);                        \
        __builtin_amdgcn_global_load_lds((const AS1 void*)(bSrc + (size_t)(C) * 8192 + 6144), \
            (AS3 void*)(&Bsm_[wid][BI][3072]), 16, 0, 0);                        \
    } while (0)

    f32x4 acc0 = {}, acc1 = {}, acc2 = {}, acc3 = {};
    f32x4 dacc = {0.f, 0.f, 0.f, 0.f};

    // Prologue: fill the 3-deep pipe (18 loads in flight).
    K3_STAGE(0, 0);
    K3_STAGE(1, 1);
    K3_STAGE(2, 2);

#define K3_BODY(C, BI, WAITSTR, DOSTAGE)                                         \
    {                                                                            \
        asm volatile(WAITSTR ::: "memory");                                      \
        __builtin_amdgcn_sched_barrier(0);                                       \
        const char* aB = &Asm_[wid][BI][0];                                      \
        f32x4 x0 = *(const f32x4*)(aB + l15 * 128 + (((quad * 2    ) ^ (l15 & 7)) << 4)); \
        f32x4 x1 = *(const f32x4*)(aB + l15 * 128 + (((quad * 2 + 1) ^ (l15 & 7)) << 4)); \
        const char* bB = &Bsm_[wid][BI][0];                                      \
        bf16x8 bf0 = *(const bf16x8*)(bB + quad * 1024 + 0 * 256 + l15 * 16);    \
        bf16x8 bf1 = *(const bf16x8*)(bB + quad * 1024 + 1 * 256 + l15 * 16);    \
        bf16x8 bf2 = *(const bf16x8*)(bB + quad * 1024 + 2 * 256 + l15 * 16);    \
        bf16x8 bf3 = *(const bf16x8*)(bB + quad * 1024 + 3 * 256 + l15 * 16);    \
        bf16x8 pv  = *(const bf16x8*)(&Psm_[(C) * 64 + quad * 16]);              \
        bf16x8 af;                                                               \
        af[0] = (__bf16)x0[0]; af[1] = (__bf16)x0[1];                            \
        af[2] = (__bf16)x0[2]; af[3] = (__bf16)x0[3];                            \
        af[4] = (__bf16)x1[0]; af[5] = (__bf16)x1[1];                            \
        af[6] = (__bf16)x1[2]; af[7] = (__bf16)x1[3];                            \
        acc0 = __builtin_amdgcn_mfma_f32_16x16x32_bf16(af, bf0, acc0, 0, 0, 0);  \
        acc1 = __builtin_amdgcn_mfma_f32_16x16x32_bf16(af, bf1, acc1, 0, 0, 0);  \
        acc2 = __builtin_amdgcn_mfma_f32_16x16x32_bf16(af, bf2, acc2, 0, 0, 0);  \
        acc3 = __builtin_amdgcn_mfma_f32_16x16x32_bf16(af, bf3, acc3, 0, 0, 0);  \
        dacc = __builtin_amdgcn_mfma_f32_16x16x32_bf16(af, pv,  dacc, 0, 0, 0);  \
        if (DOSTAGE) {                                                           \
            asm volatile("s_waitcnt lgkmcnt(0)" ::: "memory");                   \
            __builtin_amdgcn_sched_barrier(0);                                   \
            K3_STAGE(BI, (C) + 3);                                               \
        }                                                                        \
    }

    // Main loop c = 0..60: steady state, wait vmcnt(12) (= chunks c+1,c+2 in
    // flight, 6 loads each), restage into the buffer just consumed.
    int bi = 0;
    for (int c = 0; c < 61; ++c) {
        K3_BODY(c, bi, "s_waitcnt vmcnt(12)", 1)
        bi = (bi == 2) ? 0 : bi + 1;
    }
    // Peeled tail: no more staging; outstanding-newer shrinks 2 -> 1 -> 0.
    K3_BODY(61, 1, "s_waitcnt vmcnt(12)", 0)
    K3_BODY(62, 2, "s_waitcnt vmcnt(6)",  0)
    K3_BODY(63, 0, "s_waitcnt vmcnt(0)",  0)

#undef K3_BODY
#undef K3_STAGE

    // Epilogue: divide by per-row denominator (C/D row = quad*4+g holds the
    // matching dacc[g] in every lane) and store final f32.
#pragma unroll
    for (int g = 0; g < 4; ++g) {
        const float inv = 1.0f / dacc[g];
        float* orow = out + ((size_t)b * N + row0 + quad * 4 + g) * F
                    + wn * 64 + l15;
        orow[0]  = acc0[g] * inv;
        orow[16] = acc1[g] * inv;
        orow[32] = acc2[g] * inv;
        orow[48] = acc3[g] * inv;
    }
}

// ---------------------------------------------------------------------------
extern "C" void kernel_launch(void* const* d_in, const int* in_sizes, int n_in,
                              void* d_out, int out_size, void* d_ws, size_t ws_size,
                              hipStream_t stream) {
    const float* h   = (const float*)d_in[0];
    const float* adj = (const float*)d_in[1];
    const float* W   = (const float*)d_in[2];
    const float* a   = (const float*)d_in[3];
    float* out = (float*)d_out;

    unsigned short* Wb2 = (unsigned short*)d_ws;                        // 4 MB
    unsigned short* p16 = (unsigned short*)((char*)d_ws + (4u << 20));  // 32 KB

    k1_wh<<<NB * N / 64, 256, 0, stream>>>(h, W, a, Wb2, p16);
    k3_fused<<<NB * 64, 256, 0, stream>>>(adj, Wb2, p16, out);
}

// Round 5
// 221.676 us; speedup vs baseline: 1.1938x; 1.0443x over previous
//
#include <hip/hip_runtime.h>
#include <stdint.h>

#define AS1 __attribute__((address_space(1)))
#define AS3 __attribute__((address_space(3)))

typedef __bf16 bf16x8 __attribute__((ext_vector_type(8)));
typedef float f32x4 __attribute__((ext_vector_type(4)));

constexpr int NB = 8;     // batches
constexpr int N  = 2048;  // nodes
constexpr int F  = 128;   // features (in == out)

__device__ __forceinline__ unsigned short bf16r(float f) {
    unsigned u = __float_as_uint(f);
    return (unsigned short)((u + 0x7FFFu + ((u >> 16) & 1u)) >> 16);
}
__device__ __forceinline__ float bf2f(unsigned short s) {
    return __uint_as_float(((unsigned)s) << 16);
}

// ---------------------------------------------------------------------------
// Wb2 element layout (MFMA-B-operand native, linear in k-chunks):
//   byte(b, n, o) = b*N*F*2 + (n>>3)*2048 + o*16 + (n&7)*2
// BK=64 chunk c = contiguous 16384 B at b*N*F*2 + c*16384.
// ---------------------------------------------------------------------------

// K1 (fused): Wh = h @ W^T;  e = Wh @ a2;  p = exp(e);
//   p16 = bf16(p);  Wb2 = bf16(bf2f(p16) * Wh)        [unchanged, proven]
__global__ __launch_bounds__(256) void k1_wh(const float* __restrict__ h,
                                             const float* __restrict__ W,
                                             const float* __restrict__ a,
                                             unsigned short* __restrict__ Wb2,
                                             unsigned short* __restrict__ p16) {
    __shared__ float epart[2][64];

    const int tid  = threadIdx.x;
    const int lane = tid & 63, wid = tid >> 6;
    const int quad = lane >> 4, l15 = lane & 15;
    const int wm = wid >> 1, wn = wid & 1;
    const int m0 = blockIdx.x * 64;
    const int batch = m0 >> 11;
    const int nbase = m0 & 2047;

    f32x4 acc[2][4] = {};

#pragma unroll
    for (int kk = 0; kk < 4; ++kk) {
        const int k = kk * 32 + quad * 8;
        bf16x8 afr[2], bfr[4];
#pragma unroll
        for (int rt = 0; rt < 2; ++rt) {
            const float* src = h + (size_t)(m0 + wm * 32 + rt * 16 + l15) * F + k;
            float4 x0 = *(const float4*)src;
            float4 x1 = *(const float4*)(src + 4);
            afr[rt][0] = (__bf16)x0.x; afr[rt][1] = (__bf16)x0.y;
            afr[rt][2] = (__bf16)x0.z; afr[rt][3] = (__bf16)x0.w;
            afr[rt][4] = (__bf16)x1.x; afr[rt][5] = (__bf16)x1.y;
            afr[rt][6] = (__bf16)x1.z; afr[rt][7] = (__bf16)x1.w;
        }
#pragma unroll
        for (int ct = 0; ct < 4; ++ct) {
            const int o = wn * 64 + ct * 16 + l15;
            const float* src = W + (size_t)o * F + k;
            float4 x0 = *(const float4*)src;
            float4 x1 = *(const float4*)(src + 4);
            bfr[ct][0] = (__bf16)x0.x; bfr[ct][1] = (__bf16)x0.y;
            bfr[ct][2] = (__bf16)x0.z; bfr[ct][3] = (__bf16)x0.w;
            bfr[ct][4] = (__bf16)x1.x; bfr[ct][5] = (__bf16)x1.y;
            bfr[ct][6] = (__bf16)x1.z; bfr[ct][7] = (__bf16)x1.w;
        }
#pragma unroll
        for (int rt = 0; rt < 2; ++rt)
#pragma unroll
            for (int ct = 0; ct < 4; ++ct)
                acc[rt][ct] = __builtin_amdgcn_mfma_f32_16x16x32_bf16(
                    afr[rt], bfr[ct], acc[rt][ct], 0, 0, 0);
    }

    float a2v[4];
#pragma unroll
    for (int ct = 0; ct < 4; ++ct) a2v[ct] = a[F + wn * 64 + ct * 16 + l15];

    float ep[2][4];
#pragma unroll
    for (int rt = 0; rt < 2; ++rt)
#pragma unroll
        for (int g = 0; g < 4; ++g) {
            float s = 0.f;
#pragma unroll
            for (int ct = 0; ct < 4; ++ct) s += acc[rt][ct][g] * a2v[ct];
            ep[rt][g] = s;
        }
#pragma unroll
    for (int m = 1; m < 16; m <<= 1)
#pragma unroll
        for (int rt = 0; rt < 2; ++rt)
#pragma unroll
            for (int g = 0; g < 4; ++g)
                ep[rt][g] += __shfl_xor(ep[rt][g], m);

    if (l15 == 0)
#pragma unroll
        for (int rt = 0; rt < 2; ++rt)
#pragma unroll
            for (int g = 0; g < 4; ++g)
                epart[wn][wm * 32 + rt * 16 + quad * 4 + g] = ep[rt][g];
    __syncthreads();

#pragma unroll
    for (int rt = 0; rt < 2; ++rt)
#pragma unroll
        for (int ct = 0; ct < 4; ++ct) {
            const int o  = wn * 64 + ct * 16 + l15;
            const int r0 = wm * 32 + rt * 16 + quad * 4;
            const int n0 = nbase + r0;
            ushort4 v;
#pragma unroll
            for (int g = 0; g < 4; ++g) {
                const float e  = epart[0][r0 + g] + epart[1][r0 + g];
                const float pf = bf2f(bf16r(expf(e)));
                (&v.x)[g] = bf16r(pf * acc[rt][ct][g]);
            }
            size_t off = (size_t)batch * N * F + (size_t)(n0 >> 3) * 1024 + o * 8 + (n0 & 7);
            *(ushort4*)&Wb2[off] = v;
        }

    if (tid < 64) {
        const float e = epart[0][tid] + epart[1][tid];
        p16[batch * N + nbase + tid] = bf16r(expf(e));
    }
}

// K3 v4: m201-faithful counted-vmcnt pipeline, BLOCK-SHARED ring buffers,
// compile-time buffer indices, raw s_barrier (no waitcnt attached).
//   out[b][i][o] = (sum_j adj[b][i][j]*Wb2[j][o]) / (sum_j adj[b][i][j]*p[j])
// R4 post-mortem: wave-private buffers + runtime ring index let the compiler
// serialize gll->ds_read (aliasing unprovable) -> 77 us, L3-warm invariant.
// This version is the proven template: per chunk each wave issues its OWN 6
// global_load_lds into a shared 24KB buffer; consumption = own vmcnt(12)
// (2 newer chunks x 6 loads) + s_barrier (=> all waves' loads landed).
// Second barrier before restaging the just-consumed buffer (WAR-safe).
// Loads stay in flight across barriers; vmcnt never drains to 0 mid-loop.
// Block = 32 rows x full-j, BK=64, 32 chunks, ring of 3. Grid 512, b=blk&7
// XCD-pins batch (Wb2 slice 512KB L2-resident). LDS = 3x24KB + p 4KB = 76KB
// -> 2 blk/CU, 8 waves/CU. A staged XOR-pre-swizzled (slot g of row r holds
// global granule g^(r&15), 16B granules -> both A and B LDS reads are
// bank-uniform). Per-CU A-stream 512KB @10B/cyc => ~22us floor; depth-3
// pipeline (4900 cyc) >> 900-cyc HBM latency => latency fully hidden.
__global__ __launch_bounds__(256, 2) void k3_fused(const float* __restrict__ adj,
                                                   const unsigned short* __restrict__ Wb2,
                                                   const unsigned short* __restrict__ p16,
                                                   float* __restrict__ out) {
    __shared__ __align__(16) char Asm_[3][8192];    // 32 rows x 64 k f32, swizzled
    __shared__ __align__(16) char Bsm_[3][16384];   // 64 k x 128 o bf16, linear image
    __shared__ __align__(16) char Psm_[4096];       // 2048 x bf16

    const int tid  = threadIdx.x;
    const int lane = tid & 63, wid = tid >> 6;
    const int quad = lane >> 4, l15 = lane & 15;
    const int wm = wid >> 1, wn = wid & 1;
    const int b  = blockIdx.x & 7;
    const int it = blockIdx.x >> 3;        // 0..63
    const int i0 = it * 32;
    const int rowL = wm * 16 + l15;        // this lane's A row within the tile

    // A stage sources, XOR-pre-swizzled (m173 / rule #21): gll instr s covers
    // rows (wid*2+s)*4 + (lane>>4); granule slot (lane&15) receives global
    // granule G = (lane&15) ^ (r&15). 16B granules, row = 64 f32 = 16 granules.
    const float* aSrc[2];
#pragma unroll
    for (int s = 0; s < 2; ++s) {
        const int rl = (wid * 2 + s) * 4 + (lane >> 4);
        const int G  = (lane & 15) ^ (rl & 15);
        aSrc[s] = adj + (size_t)b * N * N + (size_t)(i0 + rl) * N + G * 4;
    }
    // B stage source: linear 16KB chunk image; wave stages 4KB at wid*4096.
    const char* bSrc = (const char*)Wb2 + (size_t)b * (N * F * 2)
                     + wid * 4096 + lane * 16;
    // p16 source (4KB once, wave 0).
    const char* pSrc = (const char*)p16 + (size_t)b * N * 2 + lane * 16;

#define K3_STAGE(BI, C)                                                            \
    do {                                                                           \
        __builtin_amdgcn_global_load_lds((const AS1 void*)(aSrc[0] + (C) * 64),    \
            (AS3 void*)(&Asm_[BI][(wid * 2 + 0) * 1024]), 16, 0, 0);               \
        __builtin_amdgcn_global_load_lds((const AS1 void*)(aSrc[1] + (C) * 64),    \
            (AS3 void*)(&Asm_[BI][(wid * 2 + 1) * 1024]), 16, 0, 0);               \
        __builtin_amdgcn_global_load_lds(                                          \
            (const AS1 void*)(bSrc + (size_t)(C) * 16384 + 0 * 1024),              \
            (AS3 void*)(&Bsm_[BI][wid * 4096 + 0 * 1024]), 16, 0, 0);              \
        __builtin_amdgcn_global_load_lds(                                          \
            (const AS1 void*)(bSrc + (size_t)(C) * 16384 + 1 * 1024),              \
            (AS3 void*)(&Bsm_[BI][wid * 4096 + 1 * 1024]), 16, 0, 0);              \
        __builtin_amdgcn_global_load_lds(                                          \
            (const AS1 void*)(bSrc + (size_t)(C) * 16384 + 2 * 1024),              \
            (AS3 void*)(&Bsm_[BI][wid * 4096 + 2 * 1024]), 16, 0, 0);              \
        __builtin_amdgcn_global_load_lds(                                          \
            (const AS1 void*)(bSrc + (size_t)(C) * 16384 + 3 * 1024),              \
            (AS3 void*)(&Bsm_[BI][wid * 4096 + 3 * 1024]), 16, 0, 0);              \
    } while (0)

    f32x4 acc0 = {}, acc1 = {}, acc2 = {}, acc3 = {};
    f32x4 dacc = {0.f, 0.f, 0.f, 0.f};

    // Prologue: p (wave 0, oldest in its queue — covered by chunk-0's vmcnt
    // wait + barrier), then fill the 3-deep ring (18 gll/wave in flight).
    if (wid == 0) {
#pragma unroll
        for (int s = 0; s < 4; ++s)
            __builtin_amdgcn_global_load_lds((const AS1 void*)(pSrc + s * 1024),
                (AS3 void*)(&Psm_[s * 1024]), 16, 0, 0);
    }
    K3_STAGE(0, 0);
    K3_STAGE(1, 1);
    K3_STAGE(2, 2);

#define K3_CHUNK(C, BI, WAITSTR, DOSTAGE)                                          \
    {                                                                              \
        asm volatile(WAITSTR ::: "memory");                                        \
        __builtin_amdgcn_s_barrier();                                              \
        __builtin_amdgcn_sched_barrier(0);                                         \
        const char* aB = &Asm_[BI][0];                                             \
        const char* bB = &Bsm_[BI][0];                                             \
        _Pragma("unroll")                                                          \
        for (int ks = 0; ks < 2; ++ks) {                                           \
            f32x4 x0 = *(const f32x4*)(aB + rowL * 256                             \
                          + (((ks * 8 + quad * 2 + 0) ^ l15) << 4));               \
            f32x4 x1 = *(const f32x4*)(aB + rowL * 256                             \
                          + (((ks * 8 + quad * 2 + 1) ^ l15) << 4));               \
            bf16x8 af;                                                             \
            af[0] = (__bf16)x0[0]; af[1] = (__bf16)x0[1];                          \
            af[2] = (__bf16)x0[2]; af[3] = (__bf16)x0[3];                          \
            af[4] = (__bf16)x1[0]; af[5] = (__bf16)x1[1];                          \
            af[6] = (__bf16)x1[2]; af[7] = (__bf16)x1[3];                          \
            bf16x8 pv = *(const bf16x8*)(&Psm_[(C) * 128 + ks * 64 + quad * 16]);  \
            bf16x8 bf0 = *(const bf16x8*)(bB + ks * 8192 + quad * 2048             \
                                          + wn * 1024 + 0 * 256 + l15 * 16);       \
            bf16x8 bf1 = *(const bf16x8*)(bB + ks * 8192 + quad * 2048             \
                                          + wn * 1024 + 1 * 256 + l15 * 16);       \
            bf16x8 bf2 = *(const bf16x8*)(bB + ks * 8192 + quad * 2048             \
                                          + wn * 1024 + 2 * 256 + l15 * 16);       \
            bf16x8 bf3 = *(const bf16x8*)(bB + ks * 8192 + quad * 2048             \
                                          + wn * 1024 + 3 * 256 + l15 * 16);       \
            acc0 = __builtin_amdgcn_mfma_f32_16x16x32_bf16(af, bf0, acc0, 0, 0, 0);\
            acc1 = __builtin_amdgcn_mfma_f32_16x16x32_bf16(af, bf1, acc1, 0, 0, 0);\
            acc2 = __builtin_amdgcn_mfma_f32_16x16x32_bf16(af, bf2, acc2, 0, 0, 0);\
            acc3 = __builtin_amdgcn_mfma_f32_16x16x32_bf16(af, bf3, acc3, 0, 0, 0);\
            dacc = __builtin_amdgcn_mfma_f32_16x16x32_bf16(af, pv,  dacc, 0, 0, 0);\
        }                                                                          \
        if (DOSTAGE) {                                                             \
            __builtin_amdgcn_s_barrier();                                          \
            __builtin_amdgcn_sched_barrier(0);                                     \
            K3_STAGE(BI, (C) + 3);                                                 \
        }                                                                          \
    }

    // Main: chunks 0..28 restage c+3 (last staged = 31); ring index is
    // compile-time everywhere. Steady-state wait = vmcnt(12).
    for (int c3 = 0; c3 < 27; c3 += 3) {
        K3_CHUNK(c3 + 0, 0, "s_waitcnt vmcnt(12)", 1)
        K3_CHUNK(c3 + 1, 1, "s_waitcnt vmcnt(12)", 1)
        K3_CHUNK(c3 + 2, 2, "s_waitcnt vmcnt(12)", 1)
    }
    K3_CHUNK(27, 0, "s_waitcnt vmcnt(12)", 1)   // stages 30
    K3_CHUNK(28, 1, "s_waitcnt vmcnt(12)", 1)   // stages 31
    K3_CHUNK(29, 2, "s_waitcnt vmcnt(12)", 0)
    K3_CHUNK(30, 0, "s_waitcnt vmcnt(6)",  0)
    K3_CHUNK(31, 1, "s_waitcnt vmcnt(0)",  0)

#undef K3_CHUNK
#undef K3_STAGE

    // Epilogue: divide by per-row denominator (C/D row = quad*4+g holds the
    // matching dacc[g] in every lane) and store final f32.
#pragma unroll
    for (int g = 0; g < 4; ++g) {
        const float inv = 1.0f / dacc[g];
        float* orow = out + ((size_t)b * N + i0 + wm * 16 + quad * 4 + g) * F
                    + wn * 64 + l15;
        orow[0]  = acc0[g] * inv;
        orow[16] = acc1[g] * inv;
        orow[32] = acc2[g] * inv;
        orow[48] = acc3[g] * inv;
    }
}

// ---------------------------------------------------------------------------
extern "C" void kernel_launch(void* const* d_in, const int* in_sizes, int n_in,
                              void* d_out, int out_size, void* d_ws, size_t ws_size,
                              hipStream_t stream) {
    const float* h   = (const float*)d_in[0];
    const float* adj = (const float*)d_in[1];
    const float* W   = (const float*)d_in[2];
    const float* a   = (const float*)d_in[3];
    float* out = (float*)d_out;

    unsigned short* Wb2 = (unsigned short*)d_ws;                        // 4 MB
    unsigned short* p16 = (unsigned short*)((char*)d_ws + (4u << 20));  // 32 KB

    k1_wh<<<NB * N / 64, 256, 0, stream>>>(h, W, a, Wb2, p16);
    k3_fused<<<NB * 64, 256, 0, stream>>>(adj, Wb2, p16, out);
}